// Round 7
// baseline (146.052 us; speedup 1.0000x reference)
//
#include <hip/hip_runtime.h>

// AQLM dequant: codes [8192,1024,2] i32, codebooks [2,65536,1,8] f32,
// scales [8192,1,1,1] f32 -> out [8192,8192] f32.
// out[o, i*8+j] = (cb0[codes[o,i,0]][j] + cb1[codes[o,i,1]][j]) * scales[o]
//
// Round 7: r4 config (fp32 codebooks, slot-indexed, lane-paired gathers,
// nt stores, no convert pre-pass — best measured, 127.5us) with BATCH 4->8.
// Single-variable A/B to test the latency/outstanding-miss theory: each
// thread runs 8 independent chains (8 code loads -> 16 gathers -> 8 stores),
// ~1.7x in-flight gather requests per CU vs r4.
// If MLP-limited -> ~110us. If flat -> shared TA/L1 service ceiling.

#define O_GROUPS 8192
#define I_GROUPS 1024
#define CB_SIZE  65536
#define BATCH    8

typedef float f32x4 __attribute__((ext_vector_type(4)));
typedef int   i32x2 __attribute__((ext_vector_type(2)));

__global__ __launch_bounds__(256) void aqlm_dequant_kernel(
    const i32x2* __restrict__ codes,   // [O*I] code pairs
    const f32x4* __restrict__ cb,      // [2*CB_SIZE*2] float4 view of codebooks
    const float* __restrict__ scales,  // [O]
    f32x4*       __restrict__ out)     // [O*I*2]  slot-indexed, 16B per slot
{
    const int tid  = threadIdx.x;
    const int base = blockIdx.x * (256 * BATCH) + tid;  // slot idx, coalesced per k

    int   slot[BATCH];
    i32x2 c[BATCH];
    // phase 1: 8 independent streaming code loads
    #pragma unroll
    for (int k = 0; k < BATCH; ++k) {
        slot[k] = base + k * 256;
        c[k] = __builtin_nontemporal_load(&codes[slot[k] >> 1]);  // pair shares 8B
    }

    // phase 2: 16 independent gathers (lane pairs adjacent within a line)
    f32x4 a[BATCH], b[BATCH];
    #pragma unroll
    for (int k = 0; k < BATCH; ++k) {
        const int h = slot[k] & 1;                       // which 16B half-entry
        a[k] = cb[(size_t)c[k].x * 2 + h];               // codebook 0
        b[k] = cb[((size_t)CB_SIZE + c[k].y) * 2 + h];   // codebook 1
    }

    // phase 3: combine + streaming store (lanes write consecutive 16B)
    #pragma unroll
    for (int k = 0; k < BATCH; ++k) {
        const float s = scales[slot[k] >> 11];           // o = slot >> 11
        f32x4 r = (a[k] + b[k]) * s;
        __builtin_nontemporal_store(r, &out[slot[k]]);
    }
}

extern "C" void kernel_launch(void* const* d_in, const int* in_sizes, int n_in,
                              void* d_out, int out_size, void* d_ws, size_t ws_size,
                              hipStream_t stream) {
    const i32x2* codes  = (const i32x2*)d_in[0];
    const f32x4* cb     = (const f32x4*)d_in[1];
    const float* scales = (const float*)d_in[2];
    f32x4*       out    = (f32x4*)d_out;

    const int total_slots = O_GROUPS * I_GROUPS * 2;    // 16777216
    const int block = 256;
    const int grid  = total_slots / (block * BATCH);    // 8192, exact
    aqlm_dequant_kernel<<<grid, block, 0, stream>>>(codes, cb, scales, out);
}

// Round 9
// 135.852 us; speedup vs baseline: 1.0751x; 1.0751x over previous
//
#include <hip/hip_runtime.h>

// AQLM dequant: codes [8192,1024,2] i32, codebooks [2,65536,1,8] f32,
// scales [8192,1,1,1] f32 -> out [8192,8192] f32.
// out[o, i*8+j] = (cb0[codes[o,i,0]][j] + cb1[codes[o,i,1]][j]) * scales[o]
//
// Round 9: L1-bypass gathers. Every prior round kept default-cached gathers:
// ~16.8M random entry-touches over a 4 MiB footprint -> ~0% L1 hit rate ->
// each touch costs an L1 tag lookup + full 128B L2->L1 line fill (2.15 GB
// fill traffic) for 16-32B of useful data. Fix: gather via inline-asm
// `global_load_dwordx4 ... sc0` (load-side sc0 = force L1 miss, serve from
// L2 -- coherence-safe, unlike r8's store-side sc1 which corrupted output).
// Rule #18: asm loads aren't vmcnt-tracked, so all gathers are issued, then
// one `s_waitcnt vmcnt(0)` + sched_barrier(0) before consumption.
// Otherwise identical to r4 (best measured, 127.5us): fp32 codebook,
// slot-indexed, lane-paired, BATCH=4, nt stores.

#define O_GROUPS 8192
#define I_GROUPS 1024
#define CB_SIZE  65536
#define BATCH    4

typedef float f32x4 __attribute__((ext_vector_type(4)));
typedef int   i32x2 __attribute__((ext_vector_type(2)));

// 16B gather that bypasses L1 (sc0): served directly from L2.
__device__ __forceinline__ void gload16_sc0(const f32x4* p, f32x4& d) {
    asm volatile("global_load_dwordx4 %0, %1, off sc0"
                 : "=&v"(d) : "v"(p) : "memory");
}

__global__ __launch_bounds__(256) void aqlm_dequant_kernel(
    const i32x2* __restrict__ codes,   // [O*I] code pairs
    const f32x4* __restrict__ cb,      // [2*CB_SIZE*2] float4 view of codebooks
    const float* __restrict__ scales,  // [O]
    f32x4*       __restrict__ out)     // [O*I*2]  slot-indexed, 16B per slot
{
    const int tid  = threadIdx.x;
    const int base = blockIdx.x * (256 * BATCH) + tid;  // slot idx, coalesced per k

    int   slot[BATCH];
    i32x2 c[BATCH];
    // phase 1: 4 independent streaming code loads (compiler-tracked)
    #pragma unroll
    for (int k = 0; k < BATCH; ++k) {
        slot[k] = base + k * 256;
        c[k] = __builtin_nontemporal_load(&codes[slot[k] >> 1]);  // pair shares 8B
    }

    // phase 2: issue all 8 L1-bypassing gathers (lane pairs adjacent in a line)
    f32x4 a[BATCH], b[BATCH];
    #pragma unroll
    for (int k = 0; k < BATCH; ++k) {
        const int h = slot[k] & 1;                       // which 16B half-entry
        gload16_sc0(&cb[(size_t)c[k].x * 2 + h], a[k]);              // codebook 0
        gload16_sc0(&cb[((size_t)CB_SIZE + c[k].y) * 2 + h], b[k]);  // codebook 1
    }

    // phase 3: drain our untracked asm loads, fence scheduling (rule #18)
    asm volatile("s_waitcnt vmcnt(0)" ::: "memory");
    __builtin_amdgcn_sched_barrier(0);

    // phase 4: combine + coherent streaming store (lanes write consecutive 16B)
    #pragma unroll
    for (int k = 0; k < BATCH; ++k) {
        const float s = scales[slot[k] >> 11];           // o = slot >> 11
        f32x4 r = (a[k] + b[k]) * s;
        __builtin_nontemporal_store(r, &out[slot[k]]);
    }
}

extern "C" void kernel_launch(void* const* d_in, const int* in_sizes, int n_in,
                              void* d_out, int out_size, void* d_ws, size_t ws_size,
                              hipStream_t stream) {
    const i32x2* codes  = (const i32x2*)d_in[0];
    const f32x4* cb     = (const f32x4*)d_in[1];
    const float* scales = (const float*)d_in[2];
    f32x4*       out    = (f32x4*)d_out;

    const int total_slots = O_GROUPS * I_GROUPS * 2;    // 16777216
    const int block = 256;
    const int grid  = total_slots / (block * BATCH);    // 16384, exact
    aqlm_dequant_kernel<<<grid, block, 0, stream>>>(codes, cb, scales, out);
}

// Round 10
// 127.610 us; speedup vs baseline: 1.1445x; 1.0646x over previous
//
#include <hip/hip_runtime.h>

// AQLM dequant: codes [8192,1024,2] i32, codebooks [2,65536,1,8] f32,
// scales [8192,1,1,1] f32 -> out [8192,8192] f32.
// out[o, i*8+j] = (cb0[codes[o,i,0]][j] + cb1[codes[o,i,1]][j]) * scales[o]
//
// Round 10 = exact r4 config (best measured: 127.5us). Structural ceiling
// analysis: ~16.8M random distinct-line codebook touches must each be
// serviced by L2 at line granularity (L1 hit ~0 at 4 MiB footprint, L2 hit
// ~96% per r2 FETCH_SIZE); L2 slot arithmetic puts that + 452 MB stream
// traffic at ~100% of per-XCD channel capacity at ~128us. Tested-invariant
// knobs: gather count (r3), bytes/footprint (r5/r6), store flavor/pattern
// (r6), MLP x8 (r7), L1 bypass (r9). Sort-based or LDS-chunked restructures
// add >=80us of stream traffic (net worse). This is the roofline for the
// unsorted random-gather pattern.
//
// Structure: 2 lanes per (o,i) group (each owns one 16B half of the 32B
// entry; pairs coalesce within a line -> one 128B fill per entry), BATCH=4
// independent chains per thread for MLP, slot-indexed fully-coalesced 16B
// nt stores, nt code loads.

#define O_GROUPS 8192
#define I_GROUPS 1024
#define CB_SIZE  65536
#define BATCH    4

typedef float f32x4 __attribute__((ext_vector_type(4)));
typedef int   i32x2 __attribute__((ext_vector_type(2)));

__global__ __launch_bounds__(256) void aqlm_dequant_kernel(
    const i32x2* __restrict__ codes,   // [O*I] code pairs
    const f32x4* __restrict__ cb,      // [2*CB_SIZE*2] float4 view of codebooks
    const float* __restrict__ scales,  // [O]
    f32x4*       __restrict__ out)     // [O*I*2]  slot-indexed, 16B per slot
{
    const int tid  = threadIdx.x;
    const int base = blockIdx.x * (256 * BATCH) + tid;  // slot idx, coalesced per k

    int   slot[BATCH];
    i32x2 c[BATCH];
    // phase 1: 4 independent streaming code loads
    #pragma unroll
    for (int k = 0; k < BATCH; ++k) {
        slot[k] = base + k * 256;
        c[k] = __builtin_nontemporal_load(&codes[slot[k] >> 1]);  // pair shares 8B
    }

    // phase 2: 8 independent gathers (lane pairs adjacent within a line)
    f32x4 a[BATCH], b[BATCH];
    #pragma unroll
    for (int k = 0; k < BATCH; ++k) {
        const int h = slot[k] & 1;                       // which 16B half-entry
        a[k] = cb[(size_t)c[k].x * 2 + h];               // codebook 0
        b[k] = cb[((size_t)CB_SIZE + c[k].y) * 2 + h];   // codebook 1
    }

    // phase 3: combine + streaming store (lanes write consecutive 16B)
    #pragma unroll
    for (int k = 0; k < BATCH; ++k) {
        const float s = scales[slot[k] >> 11];           // o = slot >> 11
        f32x4 r = (a[k] + b[k]) * s;
        __builtin_nontemporal_store(r, &out[slot[k]]);
    }
}

extern "C" void kernel_launch(void* const* d_in, const int* in_sizes, int n_in,
                              void* d_out, int out_size, void* d_ws, size_t ws_size,
                              hipStream_t stream) {
    const i32x2* codes  = (const i32x2*)d_in[0];
    const f32x4* cb     = (const f32x4*)d_in[1];
    const float* scales = (const float*)d_in[2];
    f32x4*       out    = (f32x4*)d_out;

    const int total_slots = O_GROUPS * I_GROUPS * 2;    // 16777216
    const int block = 256;
    const int grid  = total_slots / (block * BATCH);    // 16384, exact
    aqlm_dequant_kernel<<<grid, block, 0, stream>>>(codes, cb, scales, out);
}